// Round 1
// baseline (4247.461 us; speedup 1.0000x reference)
//
#include <hip/hip_runtime.h>
#include <cstdint>
#include <cstddef>

#define BB 128
#define NN 1024
#define NI 64
#define TT 512
#define MAXNNZ 16384

// ws layout (bytes)
#define WS_XSTATE 0u        // [BB*NN] f32 = 524288
#define WS_OFFS   524288u   // int[1025]
#define WS_CNT    532480u   // int[1024]
#define WS_IDX    536576u   // u16[MAXNNZ] = 32768
#define WS_VAL    569344u   // f32[MAXNNZ] = 65536
#define WS_U      1048576u  // U chunk [Tc*BB*NN] f32

// ---------- sparse build ----------
__global__ __launch_bounds__(64) void k_count(const float* __restrict__ W, int* __restrict__ cnt) {
    int col = blockIdx.x * 64 + threadIdx.x;
    int c = 0;
    for (int k = 0; k < NN; ++k) c += (W[(size_t)k * NN + col] != 0.0f) ? 1 : 0;
    cnt[col] = c;
}

__global__ __launch_bounds__(1024) void k_scan(const int* __restrict__ cnt, int* __restrict__ offs) {
    __shared__ int s[NN];
    int tid = threadIdx.x;
    s[tid] = cnt[tid];
    __syncthreads();
    for (int d = 1; d < NN; d <<= 1) {
        int v = (tid >= d) ? s[tid - d] : 0;
        __syncthreads();
        s[tid] += v;
        __syncthreads();
    }
    int incl = s[tid];
    offs[tid + 1] = (incl < MAXNNZ) ? incl : MAXNNZ;
    if (tid == 0) offs[0] = 0;
}

__global__ __launch_bounds__(64) void k_fill(const float* __restrict__ W, const int* __restrict__ offs,
                                             unsigned short* __restrict__ idx, float* __restrict__ val) {
    int col = blockIdx.x * 64 + threadIdx.x;
    int pos = offs[col];
    int end = offs[col + 1];
    for (int k = 0; k < NN; ++k) {
        float w = W[(size_t)k * NN + col];
        if (w != 0.0f) {
            if (pos < end) { idx[pos] = (unsigned short)k; val[pos] = w; ++pos; }
        }
    }
}

// ---------- input projection: U[tt][b][n] = sum_i In[b][i][t0+tt] * Win[i][n] ----------
__global__ __launch_bounds__(256) void k_uproj(const float* __restrict__ In, const float* __restrict__ Win,
                                               float* __restrict__ U, int t0) {
    int tt = blockIdx.x >> 2;
    int bq = blockIdx.x & 3;
    int t  = t0 + tt;
    int b0 = bq * 32;
    __shared__ float s[32][NI];
    int tid = threadIdx.x;
    for (int q = tid; q < 32 * NI; q += 256) {
        int j = q >> 6, i = q & 63;
        s[j][i] = In[((size_t)(b0 + j) * NI + i) * TT + t];
    }
    __syncthreads();
    const float4* W4 = (const float4*)Win;
    float4* U4 = (float4*)U;
    for (int bt = 0; bt < 32; bt += 8) {
        float4 acc[8];
#pragma unroll
        for (int j = 0; j < 8; ++j) acc[j] = make_float4(0.f, 0.f, 0.f, 0.f);
        for (int i = 0; i < NI; ++i) {
            float4 w = W4[i * (NN / 4) + tid];
#pragma unroll
            for (int j = 0; j < 8; ++j) {
                float sv = s[bt + j][i];
                acc[j].x = fmaf(w.x, sv, acc[j].x);
                acc[j].y = fmaf(w.y, sv, acc[j].y);
                acc[j].z = fmaf(w.z, sv, acc[j].z);
                acc[j].w = fmaf(w.w, sv, acc[j].w);
            }
        }
#pragma unroll
        for (int j = 0; j < 8; ++j)
            U4[((size_t)tt * BB + (b0 + bt + j)) * (NN / 4) + tid] = acc[j];
    }
}

// ---------- recurrence ----------
struct __align__(8) Ent { float v; int k; };

__device__ __forceinline__ float fast_tanh(float z) {
    float a = fabsf(z) * 2.885390082f;       // 2*log2(e)
    a = fminf(a, 60.0f);
    float e = __builtin_amdgcn_exp2f(a);     // e^{2|z|}
    float r = 1.0f - __fdividef(2.0f, e + 1.0f);
    return z < 0.0f ? -r : r;
}

__global__ __launch_bounds__(256) void k_step(const float* __restrict__ U,
        const int* __restrict__ offs, const unsigned short* __restrict__ gidx,
        const float* __restrict__ gval, float* __restrict__ out,
        float* __restrict__ xstate, int t0, int Tc) {
    __shared__ float4 xs4[NN / 4];           // 4 KB  (x for this batch row)
    __shared__ Ent ent[MAXNNZ];              // 128 KB (packed CSC of W)
    int b = blockIdx.x, tid = threadIdx.x;
    int nnz = offs[NN];
    for (int e = tid; e < nnz; e += 256) {
        Ent q; q.v = gval[e]; q.k = (int)gidx[e];
        ent[e] = q;
    }
    if (t0 == 0) xs4[tid] = make_float4(0.f, 0.f, 0.f, 0.f);
    else         xs4[tid] = ((const float4*)xstate)[b * (NN / 4) + tid];

    int n0 = tid * 4;
    int s0 = offs[n0], s1 = offs[n0 + 1], s2 = offs[n0 + 2], s3 = offs[n0 + 3], s4e = offs[n0 + 4];
    const float* xsf = (const float*)xs4;
    const float4* U4 = (const float4*)U;
    size_t ubase = (size_t)b * (NN / 4) + tid;
    size_t ustep = (size_t)BB * (NN / 4);
    __syncthreads();

    float4 ucur = U4[ubase];
    for (int tt = 0; tt < Tc; ++tt) {
        float4 unx = make_float4(0.f, 0.f, 0.f, 0.f);
        if (tt + 1 < Tc) unx = U4[ubase + (size_t)(tt + 1) * ustep];

        float z0 = ucur.x, z1 = ucur.y, z2 = ucur.z, z3 = ucur.w;
        for (int e = s0; e < s4e; ++e) {
            Ent q = ent[e];
            float p = q.v * xsf[q.k];
            bool c1 = e < s1, c2 = e < s2, c3 = e < s3;
            z0 += (c1) ? p : 0.0f;
            z1 += (!c1 && c2) ? p : 0.0f;
            z2 += (!c2 && c3) ? p : 0.0f;
            z3 += (!c3) ? p : 0.0f;
        }
        float4 xo = xs4[tid];
        __syncthreads();
        float4 xn;
        xn.x = 0.5f * xo.x + 0.5f * fast_tanh(z0);
        xn.y = 0.5f * xo.y + 0.5f * fast_tanh(z1);
        xn.z = 0.5f * xo.z + 0.5f * fast_tanh(z2);
        xn.w = 0.5f * xo.w + 0.5f * fast_tanh(z3);
        xs4[tid] = xn;
        int t = t0 + tt;
        size_t ob = ((size_t)b * NN + n0) * TT + (size_t)t;
        out[ob]            = xn.x;
        out[ob + TT]       = xn.y;
        out[ob + 2 * TT]   = xn.z;
        out[ob + 3 * TT]   = xn.w;
        __syncthreads();
        ucur = unx;
    }
    ((float4*)xstate)[b * (NN / 4) + tid] = xs4[tid];
}

extern "C" void kernel_launch(void* const* d_in, const int* in_sizes, int n_in,
                              void* d_out, int out_size, void* d_ws, size_t ws_size,
                              hipStream_t stream) {
    const float* In  = (const float*)d_in[0];
    const float* W   = (const float*)d_in[1];
    const float* Win = (const float*)d_in[2];
    float* out = (float*)d_out;
    char* ws = (char*)d_ws;
    float* xstate      = (float*)(ws + WS_XSTATE);
    int* offs          = (int*)(ws + WS_OFFS);
    int* cnt           = (int*)(ws + WS_CNT);
    unsigned short* idx = (unsigned short*)(ws + WS_IDX);
    float* val         = (float*)(ws + WS_VAL);
    float* U           = (float*)(ws + WS_U);

    // biggest U chunk that fits in ws
    int Tc = 16;
    const int cands[6] = {512, 256, 128, 64, 32, 16};
    for (int i = 0; i < 6; ++i) {
        if ((size_t)WS_U + (size_t)cands[i] * BB * NN * 4 <= ws_size) { Tc = cands[i]; break; }
    }

    k_count<<<16, 64, 0, stream>>>(W, cnt);
    k_scan<<<1, 1024, 0, stream>>>(cnt, offs);
    k_fill<<<16, 64, 0, stream>>>(W, offs, idx, val);

    for (int t0 = 0; t0 < TT; t0 += Tc) {
        k_uproj<<<Tc * 4, 256, 0, stream>>>(In, Win, U, t0);
        k_step<<<BB, 256, 0, stream>>>(U, offs, idx, val, out, xstate, t0, Tc);
    }
}

// Round 2
// 976.838 us; speedup vs baseline: 4.3482x; 4.3482x over previous
//
#include <hip/hip_runtime.h>
#include <cstdint>
#include <cstddef>

#define BB 128
#define NN 1024
#define NI 64
#define TT 512
#define MAXNNZ 16384
#define NE 28
#define TH 16

// ws layout (bytes)
#define WS_XSTATE 0u        // [BB*NN] f32 = 524288
#define WS_OFFS   524288u   // int[1025]
#define WS_CNT    532480u   // int[1024]
#define WS_IDX    536576u   // u16[MAXNNZ] = 32768
#define WS_VAL    569344u   // f32[MAXNNZ] = 65536
#define WS_U      1048576u  // U chunk [Tc*BB*NN] f32

// ---------- sparse build ----------
__global__ __launch_bounds__(64) void k_count(const float* __restrict__ W, int* __restrict__ cnt) {
    int col = blockIdx.x * 64 + threadIdx.x;
    int c = 0;
    for (int k = 0; k < NN; ++k) c += (W[(size_t)k * NN + col] != 0.0f) ? 1 : 0;
    cnt[col] = c;
}

__global__ __launch_bounds__(1024) void k_scan(const int* __restrict__ cnt, int* __restrict__ offs) {
    __shared__ int s[NN];
    int tid = threadIdx.x;
    s[tid] = cnt[tid];
    __syncthreads();
    for (int d = 1; d < NN; d <<= 1) {
        int v = (tid >= d) ? s[tid - d] : 0;
        __syncthreads();
        s[tid] += v;
        __syncthreads();
    }
    int incl = s[tid];
    offs[tid + 1] = (incl < MAXNNZ) ? incl : MAXNNZ;
    if (tid == 0) offs[0] = 0;
}

__global__ __launch_bounds__(64) void k_fill(const float* __restrict__ W, const int* __restrict__ offs,
                                             unsigned short* __restrict__ idx, float* __restrict__ val) {
    int col = blockIdx.x * 64 + threadIdx.x;
    int pos = offs[col];
    int end = offs[col + 1];
    for (int k = 0; k < NN; ++k) {
        float w = W[(size_t)k * NN + col];
        if (w != 0.0f) {
            if (pos < end) { idx[pos] = (unsigned short)k; val[pos] = w; ++pos; }
        }
    }
}

// ---------- input projection: U[tt][b][n] = sum_i In[b][i][t0+tt] * Win[i][n] ----------
__global__ __launch_bounds__(256) void k_uproj(const float* __restrict__ In, const float* __restrict__ Win,
                                               float* __restrict__ U, int t0) {
    int tt = blockIdx.x >> 2;
    int bq = blockIdx.x & 3;
    int t  = t0 + tt;
    int b0 = bq * 32;
    __shared__ float s[32][NI];
    int tid = threadIdx.x;
    for (int q = tid; q < 32 * NI; q += 256) {
        int j = q >> 6, i = q & 63;
        s[j][i] = In[((size_t)(b0 + j) * NI + i) * TT + t];
    }
    __syncthreads();
    const float4* W4 = (const float4*)Win;
    float4* U4 = (float4*)U;
    for (int bt = 0; bt < 32; bt += 8) {
        float4 acc[8];
#pragma unroll
        for (int j = 0; j < 8; ++j) acc[j] = make_float4(0.f, 0.f, 0.f, 0.f);
        for (int i = 0; i < NI; ++i) {
            float4 w = W4[i * (NN / 4) + tid];
#pragma unroll
            for (int j = 0; j < 8; ++j) {
                float sv = s[bt + j][i];
                acc[j].x = fmaf(w.x, sv, acc[j].x);
                acc[j].y = fmaf(w.y, sv, acc[j].y);
                acc[j].z = fmaf(w.z, sv, acc[j].z);
                acc[j].w = fmaf(w.w, sv, acc[j].w);
            }
        }
#pragma unroll
        for (int j = 0; j < 8; ++j)
            U4[((size_t)tt * BB + (b0 + bt + j)) * (NN / 4) + tid] = acc[j];
    }
}

// ---------- recurrence ----------
__device__ __forceinline__ float fast_tanh(float z) {
    float a = fabsf(z) * 2.885390082f;       // 2*log2(e)
    a = fminf(a, 60.0f);
    float e = __builtin_amdgcn_exp2f(a);     // e^{2|z|}
    float r = 1.0f - __fdividef(2.0f, e + 1.0f);
    return z < 0.0f ? -r : r;
}

__global__ __launch_bounds__(1024) void k_step(const float* __restrict__ U,
        const int* __restrict__ offs, const unsigned short* __restrict__ gidx,
        const float* __restrict__ gval, float* __restrict__ out,
        float* __restrict__ xstate, int t0, int Tc) {
    __shared__ float xbuf[2][NN];            // 8 KB ping-pong x
    int b = blockIdx.x, n = threadIdx.x;

    // load this column's entries into registers (compile-time indexed)
    int o0 = offs[n];
    int cnt = offs[n + 1] - o0;
    float wv[NE];
    int ka[NE];
#pragma unroll
    for (int j = 0; j < NE; ++j) {
        if (j < cnt) { wv[j] = gval[o0 + j]; ka[j] = ((int)gidx[o0 + j]) << 2; }
        else         { wv[j] = 0.0f;         ka[j] = 0; }
    }
    // wave-uniform max entry count (early-out bound)
    int wmax = cnt;
#pragma unroll
    for (int d = 1; d < 64; d <<= 1) {
        int o = __shfl_xor(wmax, d);
        wmax = wmax > o ? wmax : o;
    }
    wmax = __builtin_amdgcn_readfirstlane(wmax);

    float x = (t0 == 0) ? 0.0f : xstate[(size_t)b * NN + n];
    xbuf[0][n] = x;
    __syncthreads();

    const float* Ub = U + (size_t)b * NN + n;
    const size_t ustep = (size_t)BB * NN;
    const char* lds0 = (const char*)&xbuf[0][0];
    float unx = Ub[0];

    for (int tb = 0; tb < Tc; tb += TH) {
        float xh[TH];
#pragma unroll
        for (int tt = 0; tt < TH; ++tt) {
            int t = tb + tt;
            float u = unx;
            if (t + 1 < Tc) unx = Ub[(size_t)(t + 1) * ustep];  // prefetch next U

            const int phofs = (tt & 1) ? (int)(NN * 4) : 0;
            float z = u;
#pragma unroll
            for (int j = 0; j < NE; ++j) {
                if (j < wmax) {
                    float xv = *(const float*)(lds0 + phofs + ka[j]);
                    z = fmaf(wv[j], xv, z);
                }
            }
            x = 0.5f * x + 0.5f * fast_tanh(z);
            xh[tt] = x;
            // write to the other buffer for next step
            ((float*)(lds0 + (phofs ^ (int)(NN * 4))))[n] = x;
            __syncthreads();
        }
        // dump 16 steps: 64 B contiguous per thread (full cache lines)
        float4* op = (float4*)(out + ((size_t)b * NN + n) * TT + (size_t)(t0 + tb));
        op[0] = make_float4(xh[0],  xh[1],  xh[2],  xh[3]);
        op[1] = make_float4(xh[4],  xh[5],  xh[6],  xh[7]);
        op[2] = make_float4(xh[8],  xh[9],  xh[10], xh[11]);
        op[3] = make_float4(xh[12], xh[13], xh[14], xh[15]);
    }
    xstate[(size_t)b * NN + n] = x;
}

extern "C" void kernel_launch(void* const* d_in, const int* in_sizes, int n_in,
                              void* d_out, int out_size, void* d_ws, size_t ws_size,
                              hipStream_t stream) {
    const float* In  = (const float*)d_in[0];
    const float* W   = (const float*)d_in[1];
    const float* Win = (const float*)d_in[2];
    float* out = (float*)d_out;
    char* ws = (char*)d_ws;
    float* xstate       = (float*)(ws + WS_XSTATE);
    int* offs           = (int*)(ws + WS_OFFS);
    int* cnt            = (int*)(ws + WS_CNT);
    unsigned short* idx = (unsigned short*)(ws + WS_IDX);
    float* val          = (float*)(ws + WS_VAL);
    float* U            = (float*)(ws + WS_U);

    // biggest U chunk that fits in ws
    int Tc = 16;
    const int cands[6] = {512, 256, 128, 64, 32, 16};
    for (int i = 0; i < 6; ++i) {
        if ((size_t)WS_U + (size_t)cands[i] * BB * NN * 4 <= ws_size) { Tc = cands[i]; break; }
    }

    k_count<<<16, 64, 0, stream>>>(W, cnt);
    k_scan<<<1, 1024, 0, stream>>>(cnt, offs);
    k_fill<<<16, 64, 0, stream>>>(W, offs, idx, val);

    for (int t0 = 0; t0 < TT; t0 += Tc) {
        k_uproj<<<Tc * 4, 256, 0, stream>>>(In, Win, U, t0);
        k_step<<<BB, 1024, 0, stream>>>(U, offs, idx, val, out, xstate, t0, Tc);
    }
}